// Round 6
// baseline (39.514 us; speedup 1.0000x reference)
//
#include <hip/hip_runtime.h>
#include <hip/hip_bf16.h>

#define HW        1659      // 21*79
#define GLYPH_DIM 1536
#define NBL       16        // batches per block
#define THREADS   1024      // 16 waves

typedef _Float16 half8  __attribute__((ext_vector_type(8)));
typedef _Float16 half2v __attribute__((ext_vector_type(2)));
typedef float    f32x4  __attribute__((ext_vector_type(4)));

__device__ __forceinline__ float tanh_f(float x) {
    // tanh(x) = 1 - 2/(e^{2x}+1); exp handles +-inf limits correctly
    float e = __expf(x + x);
    return fmaf(-2.0f, __builtin_amdgcn_rcpf(e + 1.0f), 1.0f);
}

__device__ __forceinline__ unsigned int pk(float a, float b) {
    return __builtin_bit_cast(unsigned int, __builtin_amdgcn_cvt_pkrtz(a, b));
}

__device__ __forceinline__ half8 h8(unsigned int a, unsigned int b,
                                    unsigned int c, unsigned int d) {
    uint4 u = make_uint4(a, b, c, d);
    return __builtin_bit_cast(half8, u);
}

// One block = 16 batches, fused: histogram -> sorted-unique -> emb/bag ->
// parallel P[t] = Wih@x_t + b pre-GEMM (all 16 waves) -> wave0 serial RNN
// with minimal chain: pack(h) -> 2x mfma(Whh,h,C=P[t]) -> tanh.
// Fragment k-map tau(g,j) = {4g..4g+3, 16+4g..19+4g} used consistently for A
// and B so the HW k-permutation cancels; with this tau the C/D layout
// (col=lane&15, row=(lane>>4)*4+reg) IS the next step's B-fragment layout.
__global__ __launch_bounds__(THREADS, 4) void glyph_fused(
    const int* __restrict__ gchar, const int* __restrict__ gcol,
    const float* __restrict__ ctab, const float* __restrict__ ktab,
    const float* __restrict__ Wih, const float* __restrict__ Whh,
    const float* __restrict__ bih, const float* __restrict__ bhh,
    float* __restrict__ out_h, float* __restrict__ out_emb,
    float* __restrict__ out_bag)
{
    __shared__ unsigned int   mask[NBL][48];    // 3 KB bitmap
    __shared__ unsigned short ids[NBL][64];     // 2 KB
    __shared__ int            lens[NBL];
    __shared__ uint4          P_lds[64][64];    // 64 KB: P[t] packed f16, per-lane uint4

    const int tid = threadIdx.x;
    const int b0  = blockIdx.x * NBL;
    const int n   = tid & 15, g = (tid >> 4) & 3;

    // Wih fragments + bias (every wave needs them for the P-GEMM)
    half8 wihA0, wihA1;
    f32x4 bias0, bias1;
    #pragma unroll
    for (int j = 0; j < 8; ++j) {
        int k = (j < 4) ? (4 * g + j) : (12 + 4 * g + j);   // tau(g,j)
        wihA0[j] = (_Float16)((k < 20) ? Wih[n * 20 + k] : 0.0f);
        wihA1[j] = (_Float16)((k < 20) ? Wih[(n + 16) * 20 + k] : 0.0f);
    }
    #pragma unroll
    for (int i = 0; i < 4; ++i) {
        bias0[i] = bih[4 * g + i] + bhh[4 * g + i];
        bias1[i] = bih[16 + 4 * g + i] + bhh[16 + 4 * g + i];
    }

    // ---- zero bitmasks (NBL*48 = 768 <= 1024) ----
    if (tid < NBL * 48) ((unsigned int*)mask)[tid] = 0u;
    __syncthreads();

    // ---- phase A: bitmap histogram ----
    const int4* cp = (const int4*)(gchar + (long)b0 * HW);
    const int4* kp = (const int4*)(gcol  + (long)b0 * HW);
    const int n4 = (NBL * HW) / 4;   // 6636
    for (int idx = tid; idx < n4; idx += THREADS) {
        int4 c = cp[idx];
        int4 k = kp[idx];
        int gg  = idx * 4;
        int bl0 = gg / HW;               // magic-mul div (HW constant)
        int rem = gg - bl0 * HW;
        int bl1 = bl0 + ((rem + 1) >= HW);
        int bl2 = bl0 + ((rem + 2) >= HW);
        int bl3 = bl0 + ((rem + 3) >= HW);
        int id0 = c.x * 16 + k.x;
        int id1 = c.y * 16 + k.y;
        int id2 = c.z * 16 + k.z;
        int id3 = c.w * 16 + k.w;
        atomicOr(&mask[bl0][id0 >> 5], 1u << (id0 & 31));
        atomicOr(&mask[bl1][id1 >> 5], 1u << (id1 & 31));
        atomicOr(&mask[bl2][id2 >> 5], 1u << (id2 & 31));
        atomicOr(&mask[bl3][id3 >> 5], 1u << (id3 & 31));
    }
    __syncthreads();

    // ---- phase B: first-64 sorted set bits per batch (16 half-wave groups) ----
    if (tid < NBL * 32) {
        const int bl  = tid >> 5;
        const int l32 = tid & 31;
        unsigned long long m = 0ull;
        if (l32 < 24)
            m = ((unsigned long long)mask[bl][2 * l32 + 1] << 32) |
                (unsigned long long)mask[bl][2 * l32];
        int cnt  = __popcll(m);
        int incl = cnt;
        #pragma unroll
        for (int d = 1; d < 32; d <<= 1) {
            int nb = __shfl_up(incl, d, 32);
            if (l32 >= d) incl += nb;
        }
        int excl  = incl - cnt;
        int total = __shfl(incl, 31, 32);
        if (l32 == 0) lens[bl] = min(total, 64);
        ids[bl][l32]      = GLYPH_DIM;   // sentinel prefill (same-wave order)
        ids[bl][l32 + 32] = GLYPH_DIM;
        unsigned long long mm = m;
        int r = excl;
        while (mm != 0ull && r < 64) {
            int bit = __builtin_ctzll(mm);
            ids[bl][r] = (unsigned short)(l32 * 64 + bit);
            ++r;
            mm &= (mm - 1ull);
        }
    }
    __syncthreads();

    // ---- phase C: emb/bag global outputs (one row per thread, 1024 rows) ----
    {
        const int nb = tid >> 6, r = tid & 63;
        int id = ids[nb][r];
        int ch = id >> 4;                              // pad -> 96
        int co = (id >= GLYPH_DIM) ? 16 : (id & 15);   // pad -> 16
        const float4* crow = (const float4*)(ctab + ch * 16);
        float4 c0 = crow[0], c1 = crow[1], c2 = crow[2], c3 = crow[3];
        float4 k0 = *(const float4*)(ktab + co * 4);
        float* gp = out_emb + ((long)(b0 + nb) * 64 + r) * 20;
        *(float4*)(gp + 0)  = c0;
        *(float4*)(gp + 4)  = c1;
        *(float4*)(gp + 8)  = c2;
        *(float4*)(gp + 12) = c3;
        *(float4*)(gp + 16) = k0;
        *(float2*)(out_bag + ((long)(b0 + nb) * 64 + r) * 2) =
            make_float2((float)ch, (float)co);
    }

    // ---- P-GEMM: wave w computes P[t]=Wih@x_t+b for t=4w..4w+3 (parallel).
    //      x gathered from the L1-resident tables via ids (no coherence risk).
    {
        const int w = tid >> 6;
        #pragma unroll
        for (int i = 0; i < 4; ++i) {
            int t  = 4 * w + i;
            int id = ids[n][t];
            int ch = id >> 4;
            int co = (id >= GLYPH_DIM) ? 16 : (id & 15);
            // lo half k=4g..4g+3 always within char part (<=15)
            float4 q1 = *(const float4*)(ctab + ch * 16 + 4 * g);
            float4 q2 = (g == 0) ? *(const float4*)(ktab + co * 4)
                                 : make_float4(0, 0, 0, 0);
            half8 xB = h8(pk(q1.x, q1.y), pk(q1.z, q1.w),
                          pk(q2.x, q2.y), pk(q2.z, q2.w));
            f32x4 P0 = __builtin_amdgcn_mfma_f32_16x16x32_f16(wihA0, xB, bias0, 0, 0, 0);
            f32x4 P1 = __builtin_amdgcn_mfma_f32_16x16x32_f16(wihA1, xB, bias1, 0, 0, 0);
            P_lds[t][tid & 63] = make_uint4(pk(P0[0], P0[1]), pk(P0[2], P0[3]),
                                            pk(P1[0], P1[1]), pk(P1[2], P1[3]));
        }
    }
    __syncthreads();

    // ---- serial RNN: wave0 only; chain = pack(h) -> 2 mfma -> tanh ----
    if (tid < 64) {
        half8 whhA0, whhA1;
        #pragma unroll
        for (int j = 0; j < 8; ++j) {
            int k = (j < 4) ? (4 * g + j) : (12 + 4 * g + j);
            whhA0[j] = (_Float16)Whh[n * 32 + k];
            whhA1[j] = (_Float16)Whh[(n + 16) * 32 + k];
        }
        const int len = lens[n];
        uint4 pc = P_lds[0][tid];
        f32x4 d0 = {0, 0, 0, 0}, d1 = {0, 0, 0, 0};
        for (int t = 0; t < 64; ++t) {
            uint4 pn = P_lds[(t < 63) ? t + 1 : 63][tid];   // prefetch (off-chain)
            half8 pf = __builtin_bit_cast(half8, pc);
            f32x4 c0, c1;
            #pragma unroll
            for (int i = 0; i < 4; ++i) { c0[i] = (float)pf[i]; c1[i] = (float)pf[4 + i]; }
            half8 hB = h8(pk(d0[0], d0[1]), pk(d0[2], d0[3]),
                          pk(d1[0], d1[1]), pk(d1[2], d1[3]));
            f32x4 a0 = __builtin_amdgcn_mfma_f32_16x16x32_f16(whhA0, hB, c0, 0, 0, 0);
            f32x4 a1 = __builtin_amdgcn_mfma_f32_16x16x32_f16(whhA1, hB, c1, 0, 0, 0);
            bool upd = (t < len);
            #pragma unroll
            for (int i = 0; i < 4; ++i) {
                float h0 = tanh_f(a0[i]);
                float h1 = tanh_f(a1[i]);
                d0[i] = upd ? h0 : d0[i];
                d1[i] = upd ? h1 : d1[i];
            }
            pc = pn;
        }
        float* op = out_h + (long)(b0 + n) * 32;
        #pragma unroll
        for (int i = 0; i < 4; ++i) {
            op[4 * g + i]      = d0[i];
            op[16 + 4 * g + i] = d1[i];
        }
    }
}

extern "C" void kernel_launch(void* const* d_in, const int* in_sizes, int n_in,
                              void* d_out, int out_size, void* d_ws, size_t ws_size,
                              hipStream_t stream) {
    const int* gchar = (const int*)d_in[0];
    const int* gcol  = (const int*)d_in[1];
    const float* ctab = (const float*)d_in[2];
    const float* ktab = (const float*)d_in[3];
    const float* Wih  = (const float*)d_in[4];
    const float* Whh  = (const float*)d_in[5];
    const float* bih  = (const float*)d_in[6];
    const float* bhh  = (const float*)d_in[7];

    const int B = in_sizes[0] / HW;          // 4096
    float* out_h   = (float*)d_out;                    // B*32
    float* out_emb = out_h + (long)B * 32;             // B*64*20
    float* out_bag = out_emb + (long)B * 64 * 20;      // B*64*2

    glyph_fused<<<B / NBL, THREADS, 0, stream>>>(
        gchar, gcol, ctab, ktab, Wih, Whh, bih, bhh, out_h, out_emb, out_bag);
}